// Round 1
// baseline (6878.469 us; speedup 1.0000x reference)
//
#include <hip/hip_runtime.h>

#define DIMS 3
#define NB 256
#define NN 256
#define KK 16
#define HID 64
#define EPG 8192
#define NTOT (NB*NN)
#define NE (NB*EPG)
#define LSTR 65     // LDS row stride for 64-wide tiles: bank = (n+i)%32, conflict-free
#define SSTR 17     // LDS row stride for 16-wide s tile

// d_out layout (flat concat of reference outputs, all as float)
#define PX_OFF   0          // (B*K, F, DIMS)           = 786432
#define PEI_OFF  786432     // (2, B*K*K)               = 131072
#define PEA_OFF  917504     // (B*K*K, DIMS)            = 196608
#define PB_OFF   1114112    // (B*K,)                   = 4096
#define LOSS_OFF 1118208    // scalar
#define S_OFF    1118209    // (DIMS, B, N, K)          = 3145728

template<int OUTW>
__device__ __forceinline__ void layer_step(
    int tid, int lane, int wave, int n, int jhalf,
    const int* __restrict__ rowp, const int* __restrict__ colp,
    const float* __restrict__ ap,
    const float* __restrict__ Wm, const float* __restrict__ Ws,
    const float* __restrict__ bias,
    const float* __restrict__ U,   // fcW1 + layer_row_offset*50
    float* hbuf, float* abuf, float* tpart, bool write_h)
{
    constexpr int NCOL = OUTW / 2;
    // zero agg
    for (int idx = tid; idx < NN * LSTR; idx += 512) abuf[idx] = 0.f;
    __syncthreads();
    // edge scatter: agg[rl][lane] += w * h[cl][lane]; wave w handles 1024 edges
    {
        const int e0 = wave * (EPG / 8);
        for (int j = e0; j < e0 + EPG / 8; j += 8) {
            #pragma unroll
            for (int u = 0; u < 8; ++u) {
                const int e = j + u;
                const int rl = rowp[e] & (NN - 1);
                const int cl = colp[e] & (NN - 1);
                const float w = ap[(size_t)e * 3];
                atomicAdd(&abuf[rl * LSTR + lane], w * hbuf[cl * LSTR + lane]);
            }
        }
    }
    __syncthreads();
    // dense: h_next[n][j0..j0+NCOL) = relu(agg@Wm + h@Ws + b)
    float acc[NCOL];
    const int j0 = jhalf * NCOL;
    #pragma unroll
    for (int jj = 0; jj < NCOL; ++jj) acc[jj] = bias[j0 + jj];
    for (int i = 0; i < HID; ++i) {
        const float a = abuf[n * LSTR + i];
        const float h = hbuf[n * LSTR + i];
        const float* wm = Wm + i * OUTW + j0;
        const float* ws = Ws + i * OUTW + j0;
        #pragma unroll
        for (int jj = 0; jj < NCOL; ++jj)
            acc[jj] += a * wm[jj] + h * ws[jj];
    }
    #pragma unroll
    for (int jj = 0; jj < NCOL; ++jj) acc[jj] = fmaxf(acc[jj], 0.f);
    __syncthreads();               // all reads of hbuf/abuf complete
    if (write_h) {
        #pragma unroll
        for (int jj = 0; jj < NCOL; ++jj) hbuf[n * LSTR + j0 + jj] = acc[jj];
    }
    // t += h_next @ fcW1[rows]
    #pragma unroll
    for (int jj = 0; jj < NCOL; ++jj) {
        const float hv = acc[jj];
        const float* u = U + (j0 + jj) * 50;
        #pragma unroll
        for (int q = 0; q < 50; ++q) tpart[q] += hv * u[q];
    }
    // next layer's zero+sync fences hbuf writes before edge reads
}

__launch_bounds__(512)
__global__ void gconv_kernel(
    const float* __restrict__ x,
    const float* __restrict__ edge_attr,
    const int* __restrict__ edge_index,
    const float* __restrict__ Wm0, const float* __restrict__ Ws0, const float* __restrict__ b0,
    const float* __restrict__ Wm1, const float* __restrict__ Ws1, const float* __restrict__ b1,
    const float* __restrict__ Wm2, const float* __restrict__ Ws2, const float* __restrict__ b2,
    const float* __restrict__ fcW1, const float* __restrict__ fcb1,
    const float* __restrict__ fcW2, const float* __restrict__ fcb2,
    float* __restrict__ out, float* __restrict__ entpart)
{
    __shared__ float hbuf[NN * LSTR];   // 65 KB
    __shared__ float abuf[NN * LSTR];   // 65 KB
    __shared__ float red[8];
    const int tid = threadIdx.x;
    const int bid = blockIdx.x;
    const int d = bid >> 8;
    const int b = bid & (NB - 1);
    const int lane = tid & 63;
    const int wave  = __builtin_amdgcn_readfirstlane(tid >> 6);
    const int n = tid & (NN - 1);
    const int jhalf = __builtin_amdgcn_readfirstlane(tid >> 8);

    // stage x -> hbuf
    {
        const float4* xv = (const float4*)(x + (size_t)b * NN * HID);
        #pragma unroll
        for (int it = 0; it < 8; ++it) {
            const int idx = tid + it * 512;
            const float4 v = xv[idx];
            const int r = idx >> 4;
            const int c = (idx & 15) << 2;
            float* p = &hbuf[r * LSTR + c];
            p[0] = v.x; p[1] = v.y; p[2] = v.z; p[3] = v.w;
        }
    }

    float tpart[50];
    #pragma unroll
    for (int q = 0; q < 50; ++q) tpart[q] = 0.f;

    const int* rowp = edge_index + (size_t)b * EPG;
    const int* colp = edge_index + (size_t)NE + (size_t)b * EPG;
    const float* ap = edge_attr + (size_t)b * EPG * 3 + d;

    layer_step<64>(tid, lane, wave, n, jhalf, rowp, colp, ap,
                   Wm0 + d * HID * HID, Ws0 + d * HID * HID, b0 + d * HID,
                   fcW1, hbuf, abuf, tpart, true);
    layer_step<64>(tid, lane, wave, n, jhalf, rowp, colp, ap,
                   Wm1 + d * HID * HID, Ws1 + d * HID * HID, b1 + d * HID,
                   fcW1 + 64 * 50, hbuf, abuf, tpart, true);
    layer_step<16>(tid, lane, wave, n, jhalf, rowp, colp, ap,
                   Wm2 + d * HID * KK, Ws2 + d * HID * KK, b2 + d * KK,
                   fcW1 + 128 * 50, hbuf, abuf, tpart, false);

    // combine the two t-halves per row, FC2, softmax, entropy
    if (jhalf == 1) {
        #pragma unroll
        for (int q = 0; q < 50; ++q) abuf[n * LSTR + q] = tpart[q];
    }
    __syncthreads();
    float ent_local = 0.f;
    if (jhalf == 0) {
        float logits[KK];
        #pragma unroll
        for (int kk = 0; kk < KK; ++kk) logits[kk] = fcb2[kk];
        #pragma unroll
        for (int q = 0; q < 50; ++q) {
            const float tv = tpart[q] + abuf[n * LSTR + q] + fcb1[q];
            const float* w2 = fcW2 + q * KK;
            #pragma unroll
            for (int kk = 0; kk < KK; ++kk) logits[kk] += tv * w2[kk];
        }
        float m = logits[0];
        #pragma unroll
        for (int kk = 1; kk < KK; ++kk) m = fmaxf(m, logits[kk]);
        float sum = 0.f;
        float sv[KK];
        #pragma unroll
        for (int kk = 0; kk < KK; ++kk) { sv[kk] = expf(logits[kk] - m); sum += sv[kk]; }
        const float inv = 1.f / sum;
        float* sp = out + S_OFF + ((size_t)(d * NB + b) * NN + n) * KK;
        #pragma unroll
        for (int kk = 0; kk < KK; ++kk) {
            const float s = sv[kk] * inv;
            sp[kk] = s;
            ent_local -= s * logf(s + 1e-15f);
        }
    }
    #pragma unroll
    for (int off = 32; off; off >>= 1) ent_local += __shfl_down(ent_local, off);
    if (lane == 0) red[wave] = ent_local;
    __syncthreads();
    if (tid == 0) {
        float s = 0.f;
        #pragma unroll
        for (int w = 0; w < 8; ++w) s += red[w];
        entpart[bid] = s;
    }
}

__launch_bounds__(256)
__global__ void pool_kernel(
    const float* __restrict__ x_to_pool,
    const float* __restrict__ edge_attr,
    const int* __restrict__ edge_index,
    float* __restrict__ out, float* __restrict__ modpart)
{
    __shared__ float slds[NN * SSTR];
    __shared__ float padj[KK * KK];
    __shared__ float red[4];
    const int tid = threadIdx.x;
    const int bid = blockIdx.x;
    const int d = bid >> 8;
    const int b = bid & (NB - 1);
    const int lane = tid & 63;
    const int wave = __builtin_amdgcn_readfirstlane(tid >> 6);

    {
        const float* sp = out + S_OFF + (size_t)(d * NB + b) * NN * KK;
        for (int idx = tid; idx < NN * KK; idx += 256)
            slds[(idx >> 4) * SSTR + (idx & 15)] = sp[idx];
    }
    if (tid < KK * KK) padj[tid] = 0.f;
    __syncthreads();

    const int* rowp = edge_index + (size_t)b * EPG;
    const int* colp = edge_index + (size_t)NE + (size_t)b * EPG;
    const float* ap = edge_attr + (size_t)b * EPG * 3 + d;

    // padj[k][l] = sum_e w * s[rl][k] * s[cl][l] ; lane owns (k, lg*4+j)
    {
        const int k = lane & 15;
        const int lg = lane >> 4;
        float p0 = 0.f, p1 = 0.f, p2 = 0.f, p3 = 0.f;
        const int e0 = wave * (EPG / 4);
        for (int e = e0; e < e0 + EPG / 4; e += 4) {
            #pragma unroll
            for (int u = 0; u < 4; ++u) {
                const int ee = e + u;
                const int rl = rowp[ee] & (NN - 1);
                const int cl = colp[ee] & (NN - 1);
                const float w = ap[(size_t)ee * 3];
                const float sr = slds[rl * SSTR + k] * w;
                const float* scp = &slds[cl * SSTR + lg * 4];
                p0 += sr * scp[0];
                p1 += sr * scp[1];
                p2 += sr * scp[2];
                p3 += sr * scp[3];
            }
        }
        atomicAdd(&padj[k * KK + lg * 4 + 0], p0);
        atomicAdd(&padj[k * KK + lg * 4 + 1], p1);
        atomicAdd(&padj[k * KK + lg * 4 + 2], p2);
        atomicAdd(&padj[k * KK + lg * 4 + 3], p3);
    }

    // modularity partial: sum_e w * ||s[rl]-s[cl]||^2
    float modacc = 0.f;
    for (int i = 0; i < EPG / 256; ++i) {
        const int ee = tid + (i << 8);
        const int rl = rowp[ee] & (NN - 1);
        const int cl = colp[ee] & (NN - 1);
        const float w = ap[(size_t)ee * 3];
        const float* a0 = &slds[rl * SSTR];
        const float* a1 = &slds[cl * SSTR];
        float ss = 0.f;
        #pragma unroll
        for (int kq = 0; kq < KK; ++kq) { const float df = a0[kq] - a1[kq]; ss += df * df; }
        modacc += w * ss;
    }

    // px[k][f] = sum_n s[n][k] * xtp[n][f*3+d] ; thread owns (f, kg*4+j)
    {
        const int f = tid & 63;
        const int kg = tid >> 6;
        float xa0 = 0.f, xa1 = 0.f, xa2 = 0.f, xa3 = 0.f;
        const float* xp = x_to_pool + (size_t)b * NN * (64 * DIMS) + f * DIMS + d;
        #pragma unroll 4
        for (int nn2 = 0; nn2 < NN; ++nn2) {
            const float xv = xp[(size_t)nn2 * (64 * DIMS)];
            const float* srow = &slds[nn2 * SSTR + kg * 4];
            xa0 += xv * srow[0];
            xa1 += xv * srow[1];
            xa2 += xv * srow[2];
            xa3 += xv * srow[3];
        }
        const float sc = 1.f / 16.f;  // K/N
        out[PX_OFF + ((size_t)((b * KK + kg * 4 + 0) * 64) + f) * DIMS + d] = xa0 * sc;
        out[PX_OFF + ((size_t)((b * KK + kg * 4 + 1) * 64) + f) * DIMS + d] = xa1 * sc;
        out[PX_OFF + ((size_t)((b * KK + kg * 4 + 2) * 64) + f) * DIMS + d] = xa2 * sc;
        out[PX_OFF + ((size_t)((b * KK + kg * 4 + 3) * 64) + f) * DIMS + d] = xa3 * sc;
    }

    #pragma unroll
    for (int off = 32; off; off >>= 1) modacc += __shfl_down(modacc, off);
    if (lane == 0) red[wave] = modacc;
    __syncthreads();   // also fences the padj atomics
    if (tid == 0) modpart[bid] = red[0] + red[1] + red[2] + red[3];

    // pea[((b*K+k)*K+l)*3 + d] = padj * (K/N)^2
    {
        const float v = padj[tid] * (1.f / 256.f);
        out[PEA_OFF + (size_t)((b * KK + (tid >> 4)) * KK + (tid & 15)) * DIMS + d] = v;
    }
}

__global__ void aux_kernel(float* __restrict__ out)
{
    const int idx = blockIdx.x * 256 + threadIdx.x;
    if (idx < 2 * NTOT) {
        const int r = idx & (NTOT - 1);
        const int b = r >> 8;
        const int j = r & 255;
        const int v = (idx < NTOT) ? (b * KK + (j >> 4)) : (b * KK + (j & 15));
        out[PEI_OFF + idx] = (float)v;
    } else if (idx < 2 * NTOT + NB * KK) {
        const int i = idx - 2 * NTOT;
        out[PB_OFF + i] = (float)(i >> 4);
    }
}

__global__ void loss_kernel(const float* __restrict__ entpart,
                            const float* __restrict__ modpart,
                            float* __restrict__ out)
{
    const int tid = threadIdx.x;
    float e = 0.f, m = 0.f;
    for (int i = tid; i < DIMS * NB; i += 256) { e += entpart[i]; m += modpart[i]; }
    #pragma unroll
    for (int off = 32; off; off >>= 1) { e += __shfl_down(e, off); m += __shfl_down(m, off); }
    __shared__ float er[4], mr[4];
    const int wave = tid >> 6, lane = tid & 63;
    if (lane == 0) { er[wave] = e; mr[wave] = m; }
    __syncthreads();
    if (tid == 0) {
        const float es = er[0] + er[1] + er[2] + er[3];
        const float ms = mr[0] + mr[1] + mr[2] + mr[3];
        out[LOSS_OFF] = ms / (float)NE + es / (float)(DIMS * NTOT);
    }
}

extern "C" void kernel_launch(void* const* d_in, const int* in_sizes, int n_in,
                              void* d_out, int out_size, void* d_ws, size_t ws_size,
                              hipStream_t stream)
{
    const float* x         = (const float*)d_in[0];
    const float* edge_attr = (const float*)d_in[1];
    const float* x_to_pool = (const float*)d_in[2];
    const float* Wm0 = (const float*)d_in[3];
    const float* Ws0 = (const float*)d_in[4];
    const float* b0  = (const float*)d_in[5];
    const float* Wm1 = (const float*)d_in[6];
    const float* Ws1 = (const float*)d_in[7];
    const float* b1  = (const float*)d_in[8];
    const float* Wm2 = (const float*)d_in[9];
    const float* Ws2 = (const float*)d_in[10];
    const float* b2  = (const float*)d_in[11];
    const float* fcW1= (const float*)d_in[12];
    const float* fcb1= (const float*)d_in[13];
    const float* fcW2= (const float*)d_in[14];
    const float* fcb2= (const float*)d_in[15];
    const int* edge_index = (const int*)d_in[16];
    float* out = (float*)d_out;
    float* entpart = (float*)d_ws;
    float* modpart = entpart + DIMS * NB;

    gconv_kernel<<<dim3(DIMS * NB), dim3(512), 0, stream>>>(
        x, edge_attr, edge_index,
        Wm0, Ws0, b0, Wm1, Ws1, b1, Wm2, Ws2, b2,
        fcW1, fcb1, fcW2, fcb2, out, entpart);
    pool_kernel<<<dim3(DIMS * NB), dim3(256), 0, stream>>>(
        x_to_pool, edge_attr, edge_index, out, modpart);
    aux_kernel<<<dim3((2 * NTOT + NB * KK + 255) / 256), dim3(256), 0, stream>>>(out);
    loss_kernel<<<dim3(1), dim3(256), 0, stream>>>(entpart, modpart, out);
}

// Round 2
// 3635.728 us; speedup vs baseline: 1.8919x; 1.8919x over previous
//
#include <hip/hip_runtime.h>

#define DIMS 3
#define NB 256
#define NN 256
#define KK 16
#define HID 64
#define EPG 8192
#define NTOT (NB*NN)
#define NE (NB*EPG)

// d_out layout (flat concat of reference outputs, all as float)
#define PX_OFF   0          // (B*K, F, DIMS)           = 786432
#define PEI_OFF  786432     // (2, B*K*K)               = 131072
#define PEA_OFF  917504     // (B*K*K, DIMS)            = 196608
#define PB_OFF   1114112    // (B*K,)                   = 4096
#define LOSS_OFF 1118208    // scalar
#define S_OFF    1118209    // (DIMS, B, N, K)          = 3145728

// d_ws layout (bytes)
#define REC_WS   0                        // float4[NB*EPG] packed {cl_bits, w0, w1, w2} = 32 MB
#define IPTR_WS  (33554432)               // int[NB*257]
#define ENT_WS   (33554432 + 263168)      // float[768]
#define MOD_WS   (ENT_WS + 3072)          // float[768]

// ---------------- CSR build (deterministic stable counting sort) ----------------
__launch_bounds__(256)
__global__ void csr_build(const int* __restrict__ edge_index,
                          const float* __restrict__ edge_attr,
                          float4* __restrict__ rec, int* __restrict__ indptr)
{
    __shared__ int rl[EPG];       // 32 KB
    __shared__ int cnt[256];
    __shared__ int sc[256];
    const int b = blockIdx.x;
    const int t = threadIdx.x;
    const int* rowp = edge_index + (size_t)b * EPG;
    const int* colp = edge_index + (size_t)NB * EPG + (size_t)b * EPG;
    for (int i = t; i < EPG; i += 256) rl[i] = rowp[i] & (NN - 1);
    cnt[t] = 0;
    __syncthreads();
    // histogram (int atomics: order-independent => deterministic)
    for (int i = t; i < EPG; i += 256) atomicAdd(&cnt[rl[i]], 1);
    __syncthreads();
    sc[t] = cnt[t];
    __syncthreads();
    // inclusive scan (Hillis-Steele)
    for (int ofs = 1; ofs < 256; ofs <<= 1) {
        int v = (t >= ofs) ? sc[t - ofs] : 0;
        __syncthreads();
        sc[t] += v;
        __syncthreads();
    }
    const int start = sc[t] - cnt[t];
    indptr[b * 257 + t] = start;
    if (t == 255) indptr[b * 257 + 256] = EPG;
    // stable place: scan edges in order; thread t claims its row's edges
    const float* eap = edge_attr + (size_t)b * EPG * 3;
    float4* rb = rec + (size_t)b * EPG;
    int c = start;
    for (int e4 = 0; e4 < EPG; e4 += 4) {
        const int4 r4 = *(const int4*)&rl[e4];
        const int rv[4] = {r4.x, r4.y, r4.z, r4.w};
        #pragma unroll
        for (int u = 0; u < 4; ++u) {
            if (rv[u] == t) {
                const int e = e4 + u;
                float4 r;
                r.x = __int_as_float(colp[e] & (NN - 1));
                r.y = eap[e * 3 + 0];
                r.z = eap[e * 3 + 1];
                r.w = eap[e * 3 + 2];
                rb[c++] = r;
            }
        }
    }
}

// ---------------- gconv: 3 layers + FC + softmax fused, per (d,b) block ----------------
template<int OUTW, bool WRITE_H>
__device__ __forceinline__ void layer_step(
    int t, int r, int half, int js, int je, int d,
    const float4* __restrict__ rb,
    const float* __restrict__ Wm, const float* __restrict__ Ws,
    const float* __restrict__ bias, const float* __restrict__ U,
    float4* hb4, float4* ab4, float* ulds, float* tpart)
{
    constexpr int NCOL = OUTW / 2;
    __syncthreads();                       // [A] hb stable, prev ulds readers done
    // gather agg[r][half*32 .. +32) from CSR, register-accumulated
    float ga[32];
    #pragma unroll
    for (int u = 0; u < 32; ++u) ga[u] = 0.f;
    const int cb = half * 8;
    for (int j = js; j < je; ++j) {
        const float4 e = rb[j];
        const int cl = __float_as_int(e.x);
        const float w = (d == 0) ? e.y : ((d == 1) ? e.z : e.w);
        const int base = cl * 16, sw = cl & 15;
        #pragma unroll
        for (int u = 0; u < 8; ++u) {
            const float4 h4 = hb4[base + ((cb + u) ^ sw)];
            ga[u*4+0] += w * h4.x; ga[u*4+1] += w * h4.y;
            ga[u*4+2] += w * h4.z; ga[u*4+3] += w * h4.w;
        }
    }
    {
        const int base = r * 16, sw = r & 15;
        #pragma unroll
        for (int u = 0; u < 8; ++u) {
            float4 v; v.x = ga[u*4+0]; v.y = ga[u*4+1]; v.z = ga[u*4+2]; v.w = ga[u*4+3];
            ab4[base + ((cb + u) ^ sw)] = v;
        }
    }
    // stage fcW1 slice for this layer (read after [B])
    for (int i = t; i < OUTW * 50; i += 512) ulds[i] = U[i];
    __syncthreads();                       // [B]
    // dense: h_next[r][j0..j0+NCOL) = relu(agg@Wm + h@Ws + b)
    const int j0 = half * NCOL;
    float acc[NCOL];
    #pragma unroll
    for (int jj = 0; jj < NCOL; ++jj) acc[jj] = bias[j0 + jj];
    const int rbase = r * 16, rsw = r & 15;
    for (int ic = 0; ic < 16; ++ic) {
        const float4 a4 = ab4[rbase + (ic ^ rsw)];
        const float4 h4 = hb4[rbase + (ic ^ rsw)];
        const float av[4] = {a4.x, a4.y, a4.z, a4.w};
        const float hv[4] = {h4.x, h4.y, h4.z, h4.w};
        #pragma unroll
        for (int u = 0; u < 4; ++u) {
            const int i = ic * 4 + u;
            const float a = av[u], h = hv[u];
            const float* wmr = Wm + i * OUTW + j0;
            const float* wsr = Ws + i * OUTW + j0;
            #pragma unroll
            for (int q4 = 0; q4 < NCOL / 4; ++q4) {
                const float4 wm4 = *(const float4*)(wmr + q4 * 4);
                const float4 ws4 = *(const float4*)(wsr + q4 * 4);
                acc[q4*4+0] += a * wm4.x + h * ws4.x;
                acc[q4*4+1] += a * wm4.y + h * ws4.y;
                acc[q4*4+2] += a * wm4.z + h * ws4.z;
                acc[q4*4+3] += a * wm4.w + h * ws4.w;
            }
        }
    }
    #pragma unroll
    for (int jj = 0; jj < NCOL; ++jj) acc[jj] = fmaxf(acc[jj], 0.f);
    __syncthreads();                       // [C] all hb/ab reads done
    if (WRITE_H) {
        const int base = r * 16, sw = r & 15;
        #pragma unroll
        for (int u = 0; u < NCOL / 4; ++u) {
            float4 v; v.x = acc[u*4+0]; v.y = acc[u*4+1]; v.z = acc[u*4+2]; v.w = acc[u*4+3];
            hb4[base + ((cb + u) ^ sw)] = v;
        }
    }
    // t += h_next @ fcW1[layer rows] (from LDS)
    #pragma unroll
    for (int jj = 0; jj < NCOL; ++jj) {
        const float hvv = acc[jj];
        const float* ur = ulds + (j0 + jj) * 50;
        #pragma unroll
        for (int q2 = 0; q2 < 25; ++q2) {
            const float2 u2 = *(const float2*)(ur + q2 * 2);
            tpart[q2*2+0] += hvv * u2.x;
            tpart[q2*2+1] += hvv * u2.y;
        }
    }
}

__launch_bounds__(512)
__global__ void gconv_kernel(
    const float* __restrict__ x,
    const float* __restrict__ Wm0, const float* __restrict__ Ws0, const float* __restrict__ b0,
    const float* __restrict__ Wm1, const float* __restrict__ Ws1, const float* __restrict__ b1,
    const float* __restrict__ Wm2, const float* __restrict__ Ws2, const float* __restrict__ b2,
    const float* __restrict__ fcW1, const float* __restrict__ fcb1,
    const float* __restrict__ fcW2, const float* __restrict__ fcb2,
    const float4* __restrict__ rec, const int* __restrict__ indptr,
    float* __restrict__ out, float* __restrict__ entpart)
{
    __shared__ float4 hb4[4096];   // h tile, XOR-chunk-swizzled  (64 KB)
    __shared__ float4 ab4[4096];   // agg tile / tpart exchange   (64 KB)
    __shared__ float  ulds[3200];  // fcW1 layer slice            (12.5 KB)
    __shared__ float  red[8];
    float* ab = (float*)ab4;
    const int t = threadIdx.x;
    const int bid = blockIdx.x;
    const int d = bid >> 8;
    const int b = bid & (NB - 1);
    const int r = t & (NN - 1);
    const int half = t >> 8;
    const int lane = t & 63;
    const int wave = t >> 6;

    // stage x -> hb (swizzled)
    {
        const float4* xv = (const float4*)(x + (size_t)b * NN * HID);
        #pragma unroll
        for (int it = 0; it < 8; ++it) {
            const int idx = t + it * 512;
            const int nrow = idx >> 4, c = idx & 15;
            hb4[nrow * 16 + (c ^ (nrow & 15))] = xv[idx];
        }
    }
    float tpart[50];
    #pragma unroll
    for (int q = 0; q < 50; ++q) tpart[q] = 0.f;

    const float4* rb = rec + (size_t)b * EPG;
    const int js = indptr[b * 257 + r];
    const int je = indptr[b * 257 + r + 1];

    layer_step<64, true >(t, r, half, js, je, d, rb, Wm0 + d*HID*HID, Ws0 + d*HID*HID,
                          b0 + d*HID, fcW1,            hb4, ab4, ulds, tpart);
    layer_step<64, true >(t, r, half, js, je, d, rb, Wm1 + d*HID*HID, Ws1 + d*HID*HID,
                          b1 + d*HID, fcW1 + 64*50,    hb4, ab4, ulds, tpart);
    layer_step<16, false>(t, r, half, js, je, d, rb, Wm2 + d*HID*KK,  Ws2 + d*HID*KK,
                          b2 + d*KK,  fcW1 + 128*50,   hb4, ab4, ulds, tpart);

    // exchange tpart halves via ab (layout [q][r], conflict-free)
    __syncthreads();
    if (half == 1) {
        #pragma unroll
        for (int q = 0; q < 50; ++q) ab[(q << 8) + r] = tpart[q];
    }
    __syncthreads();
    float ent_local = 0.f;
    if (half == 0) {
        float tvv[50];
        #pragma unroll
        for (int q = 0; q < 50; ++q) tvv[q] = tpart[q] + ab[(q << 8) + r] + fcb1[q];
        float logits[KK];
        #pragma unroll
        for (int kk = 0; kk < KK; ++kk) logits[kk] = fcb2[kk];
        #pragma unroll 2
        for (int q = 0; q < 50; ++q) {
            const float tv = tvv[q];
            const float* w2 = fcW2 + q * KK;
            #pragma unroll
            for (int kk = 0; kk < KK; ++kk) logits[kk] += tv * w2[kk];
        }
        float m = logits[0];
        #pragma unroll
        for (int kk = 1; kk < KK; ++kk) m = fmaxf(m, logits[kk]);
        float sum = 0.f, sv[KK];
        #pragma unroll
        for (int kk = 0; kk < KK; ++kk) { sv[kk] = expf(logits[kk] - m); sum += sv[kk]; }
        const float inv = 1.f / sum;
        float* sp = out + S_OFF + ((size_t)(d * NB + b) * NN + r) * KK;
        #pragma unroll
        for (int kk = 0; kk < KK; ++kk) {
            const float s = sv[kk] * inv;
            sp[kk] = s;
            ent_local -= s * logf(s + 1e-15f);
        }
    }
    #pragma unroll
    for (int off = 32; off; off >>= 1) ent_local += __shfl_down(ent_local, off);
    if (lane == 0) red[wave] = ent_local;
    __syncthreads();
    if (t == 0) {
        float s = 0.f;
        #pragma unroll
        for (int w = 0; w < 8; ++w) s += red[w];
        entpart[bid] = s;
    }
}

// ---------------- pool: padj = sum_r s[r] (x) G[r], G = A s ; + mod + px ----------------
#define SSTR 20
__launch_bounds__(256)
__global__ void pool_kernel(
    const float* __restrict__ x_to_pool,
    const float4* __restrict__ rec, const int* __restrict__ indptr,
    const float* __restrict__ out_s, float* __restrict__ out, float* __restrict__ modpart)
{
    __shared__ float sl[NN * SSTR];       // 20 KB
    __shared__ float gl[NN * SSTR];       // 20 KB
    __shared__ float padjw[4 * 256];      // per-wave partials (deterministic merge)
    __shared__ float red[4];
    const int t = threadIdx.x;
    const int bid = blockIdx.x;
    const int d = bid >> 8;
    const int b = bid & (NB - 1);
    const int lane = t & 63;
    const int wave = t >> 6;

    // stage s
    {
        const float4* sp4 = (const float4*)(out_s + S_OFF + (size_t)(d * NB + b) * NN * KK);
        #pragma unroll
        for (int it = 0; it < 4; ++it) {
            const int idx = t + it * 256;
            const int nrow = idx >> 2, c = idx & 3;
            *(float4*)(sl + nrow * SSTR + c * 4) = sp4[idx];
        }
    }
    __syncthreads();

    // phase 2: G gather + modularity partial (thread = row)
    const float4* rb = rec + (size_t)b * EPG;
    const int js = indptr[b * 257 + t];
    const int je = indptr[b * 257 + t + 1];
    float sr[16];
    {
        #pragma unroll
        for (int c = 0; c < 4; ++c) {
            const float4 v = *(const float4*)(sl + t * SSTR + c * 4);
            sr[c*4+0] = v.x; sr[c*4+1] = v.y; sr[c*4+2] = v.z; sr[c*4+3] = v.w;
        }
    }
    float g[16];
    #pragma unroll
    for (int k = 0; k < 16; ++k) g[k] = 0.f;
    float modacc = 0.f;
    for (int j = js; j < je; ++j) {
        const float4 e = rb[j];
        const int cl = __float_as_int(e.x);
        const float w = (d == 0) ? e.y : ((d == 1) ? e.z : e.w);
        const float* srow = sl + cl * SSTR;
        float ss = 0.f;
        #pragma unroll
        for (int c = 0; c < 4; ++c) {
            const float4 sv = *(const float4*)(srow + c * 4);
            g[c*4+0] += w * sv.x; g[c*4+1] += w * sv.y;
            g[c*4+2] += w * sv.z; g[c*4+3] += w * sv.w;
            const float d0 = sr[c*4+0] - sv.x, d1 = sr[c*4+1] - sv.y;
            const float d2 = sr[c*4+2] - sv.z, d3 = sr[c*4+3] - sv.w;
            ss += d0*d0 + d1*d1 + d2*d2 + d3*d3;
        }
        modacc += w * ss;
    }
    {
        #pragma unroll
        for (int c = 0; c < 4; ++c) {
            float4 v; v.x = g[c*4+0]; v.y = g[c*4+1]; v.z = g[c*4+2]; v.w = g[c*4+3];
            *(float4*)(gl + t * SSTR + c * 4) = v;
        }
    }
    __syncthreads();

    // phase 3: padj[k][l] = sum_r s[r][k] * G[r][l]; wave w covers r in [w*64, w*64+64)
    {
        const int k = t & 15, lg = (t >> 4) & 3;
        float p0 = 0.f, p1 = 0.f, p2 = 0.f, p3 = 0.f;
        const int r0 = wave * 64;
        for (int rr = r0; rr < r0 + 64; ++rr) {
            const float sk = sl[rr * SSTR + k];
            const float4 g4 = *(const float4*)(gl + rr * SSTR + lg * 4);
            p0 += sk * g4.x; p1 += sk * g4.y; p2 += sk * g4.z; p3 += sk * g4.w;
        }
        float* pw = padjw + wave * 256 + k * 16 + lg * 4;
        pw[0] = p0; pw[1] = p1; pw[2] = p2; pw[3] = p3;
    }

    // px[k][f] = sum_n s[n][k] * xtp[n][f*3+d]
    {
        const int f = t & 63;
        const int kg = t >> 6;
        float xa0 = 0.f, xa1 = 0.f, xa2 = 0.f, xa3 = 0.f;
        const float* xp = x_to_pool + (size_t)b * NN * (64 * DIMS) + f * DIMS + d;
        #pragma unroll 4
        for (int nn2 = 0; nn2 < NN; ++nn2) {
            const float xv = xp[(size_t)nn2 * (64 * DIMS)];
            const float4 s4 = *(const float4*)(sl + nn2 * SSTR + kg * 4);
            xa0 += xv * s4.x; xa1 += xv * s4.y; xa2 += xv * s4.z; xa3 += xv * s4.w;
        }
        const float sc = 1.f / 16.f;  // K/N
        out[PX_OFF + ((size_t)((b * KK + kg * 4 + 0) * 64) + f) * DIMS + d] = xa0 * sc;
        out[PX_OFF + ((size_t)((b * KK + kg * 4 + 1) * 64) + f) * DIMS + d] = xa1 * sc;
        out[PX_OFF + ((size_t)((b * KK + kg * 4 + 2) * 64) + f) * DIMS + d] = xa2 * sc;
        out[PX_OFF + ((size_t)((b * KK + kg * 4 + 3) * 64) + f) * DIMS + d] = xa3 * sc;
    }

    #pragma unroll
    for (int off = 32; off; off >>= 1) modacc += __shfl_down(modacc, off);
    if (lane == 0) red[wave] = modacc;
    __syncthreads();
    if (t == 0) modpart[bid] = red[0] + red[1] + red[2] + red[3];

    // pea (deterministic 4-wave merge)
    {
        const float v = (padjw[t] + padjw[256 + t] + padjw[512 + t] + padjw[768 + t]) * (1.f / 256.f);
        out[PEA_OFF + (size_t)((b * KK + (t >> 4)) * KK + (t & 15)) * DIMS + d] = v;
    }
}

__global__ void aux_kernel(float* __restrict__ out)
{
    const int idx = blockIdx.x * 256 + threadIdx.x;
    if (idx < 2 * NTOT) {
        const int r = idx & (NTOT - 1);
        const int bb = r >> 8;
        const int j = r & 255;
        const int v = (idx < NTOT) ? (bb * KK + (j >> 4)) : (bb * KK + (j & 15));
        out[PEI_OFF + idx] = (float)v;
    } else if (idx < 2 * NTOT + NB * KK) {
        const int i = idx - 2 * NTOT;
        out[PB_OFF + i] = (float)(i >> 4);
    }
}

__global__ void loss_kernel(const float* __restrict__ entpart,
                            const float* __restrict__ modpart,
                            float* __restrict__ out)
{
    const int tid = threadIdx.x;
    float e = 0.f, m = 0.f;
    for (int i = tid; i < DIMS * NB; i += 256) { e += entpart[i]; m += modpart[i]; }
    #pragma unroll
    for (int off = 32; off; off >>= 1) { e += __shfl_down(e, off); m += __shfl_down(m, off); }
    __shared__ float er[4], mr[4];
    const int wave = tid >> 6, lane = tid & 63;
    if (lane == 0) { er[wave] = e; mr[wave] = m; }
    __syncthreads();
    if (tid == 0) {
        const float es = er[0] + er[1] + er[2] + er[3];
        const float ms = mr[0] + mr[1] + mr[2] + mr[3];
        out[LOSS_OFF] = ms / (float)NE + es / (float)(DIMS * NTOT);
    }
}

extern "C" void kernel_launch(void* const* d_in, const int* in_sizes, int n_in,
                              void* d_out, int out_size, void* d_ws, size_t ws_size,
                              hipStream_t stream)
{
    const float* x         = (const float*)d_in[0];
    const float* edge_attr = (const float*)d_in[1];
    const float* x_to_pool = (const float*)d_in[2];
    const float* Wm0 = (const float*)d_in[3];
    const float* Ws0 = (const float*)d_in[4];
    const float* b0  = (const float*)d_in[5];
    const float* Wm1 = (const float*)d_in[6];
    const float* Ws1 = (const float*)d_in[7];
    const float* b1  = (const float*)d_in[8];
    const float* Wm2 = (const float*)d_in[9];
    const float* Ws2 = (const float*)d_in[10];
    const float* b2  = (const float*)d_in[11];
    const float* fcW1= (const float*)d_in[12];
    const float* fcb1= (const float*)d_in[13];
    const float* fcW2= (const float*)d_in[14];
    const float* fcb2= (const float*)d_in[15];
    const int* edge_index = (const int*)d_in[16];
    float* out = (float*)d_out;
    char* ws = (char*)d_ws;
    float4* rec   = (float4*)(ws + REC_WS);
    int*    iptr  = (int*)(ws + IPTR_WS);
    float*  entpart = (float*)(ws + ENT_WS);
    float*  modpart = (float*)(ws + MOD_WS);

    csr_build<<<dim3(NB), dim3(256), 0, stream>>>(edge_index, edge_attr, rec, iptr);
    gconv_kernel<<<dim3(DIMS * NB), dim3(512), 0, stream>>>(
        x, Wm0, Ws0, b0, Wm1, Ws1, b1, Wm2, Ws2, b2,
        fcW1, fcb1, fcW2, fcb2, rec, iptr, out, entpart);
    pool_kernel<<<dim3(DIMS * NB), dim3(256), 0, stream>>>(
        x_to_pool, rec, iptr, out, out, modpart);
    aux_kernel<<<dim3((2 * NTOT + NB * KK + 255) / 256), dim3(256), 0, stream>>>(out);
    loss_kernel<<<dim3(1), dim3(256), 0, stream>>>(entpart, modpart, out);
}

// Round 3
// 2111.440 us; speedup vs baseline: 3.2577x; 1.7219x over previous
//
#include <hip/hip_runtime.h>

#define DIMS 3
#define NB 256
#define NN 256
#define KK 16
#define HID 64
#define EPG 8192
#define NTOT (NB*NN)
#define NE (NB*EPG)

// d_out layout (flat concat of reference outputs, all as float)
#define PX_OFF   0          // (B*K, F, DIMS)           = 786432
#define PEI_OFF  786432     // (2, B*K*K)               = 131072
#define PEA_OFF  917504     // (B*K*K, DIMS)            = 196608
#define PB_OFF   1114112    // (B*K,)                   = 4096
#define LOSS_OFF 1118208    // scalar
#define S_OFF    1118209    // (DIMS, B, N, K)          = 3145728

// d_ws layout (bytes) — total ~27.5 MB
#define WREC_WS  0                 // float[3][NB*EPG] per-d edge weight (CSR order) = 24 MB
#define CLREC_WS 25165824          // uchar[NB*EPG] col-local index
#define IPTR_WS  27262976          // int[NB*257]
#define ENT_WS   27526144          // float[768]
#define MOD_WS   27529216          // float[768]
#define WC_WS    27532288          // float[144*16]  (fcW1 @ fcW2)
#define BC_WS    27541504          // float[16]      (fcb1 @ fcW2 + fcb2)

// ---------------- combined FC weights: Wc = fcW1@fcW2, bc = fcb1@fcW2+fcb2 ----------------
__global__ void fc_combine(const float* __restrict__ fcW1, const float* __restrict__ fcb1,
                           const float* __restrict__ fcW2, const float* __restrict__ fcb2,
                           float* __restrict__ wc, float* __restrict__ bc)
{
    const int t = threadIdx.x;
    for (int idx = t; idx < 144 * 16; idx += 256) {
        const int i = idx >> 4, k = idx & 15;
        float s = 0.f;
        for (int q = 0; q < 50; ++q) s += fcW1[i * 50 + q] * fcW2[q * 16 + k];
        wc[idx] = s;
    }
    if (t < 16) {
        float s = fcb2[t];
        for (int q = 0; q < 50; ++q) s += fcb1[q] * fcW2[q * 16 + t];
        bc[t] = s;
    }
}

// ---------------- CSR build (deterministic stable counting sort) ----------------
__launch_bounds__(256)
__global__ void csr_build(const int* __restrict__ edge_index,
                          const float* __restrict__ edge_attr,
                          float* __restrict__ wrec, unsigned char* __restrict__ clrec,
                          int* __restrict__ indptr)
{
    __shared__ int rl[EPG];              // 32 KB
    __shared__ unsigned char clb[EPG];   // 8 KB
    __shared__ int cnt[256];
    __shared__ int sc[256];
    const int b = blockIdx.x;
    const int t = threadIdx.x;
    const int* rowp = edge_index + (size_t)b * EPG;
    const int* colp = edge_index + (size_t)NB * EPG + (size_t)b * EPG;
    for (int i = t; i < EPG; i += 256) {
        rl[i] = rowp[i] & (NN - 1);
        clb[i] = (unsigned char)(colp[i] & (NN - 1));
    }
    cnt[t] = 0;
    __syncthreads();
    for (int i = t; i < EPG; i += 256) atomicAdd(&cnt[rl[i]], 1);
    __syncthreads();
    sc[t] = cnt[t];
    __syncthreads();
    for (int ofs = 1; ofs < 256; ofs <<= 1) {
        int v = (t >= ofs) ? sc[t - ofs] : 0;
        __syncthreads();
        sc[t] += v;
        __syncthreads();
    }
    const int start = sc[t] - cnt[t];
    indptr[b * 257 + t] = start;
    if (t == 255) indptr[b * 257 + 256] = EPG;
    // stable claim: scan edges in order; thread t takes its row's edges
    const float* eap = edge_attr + (size_t)b * EPG * 3;
    float* w0 = wrec + (size_t)b * EPG;
    float* w1 = wrec + (size_t)NB * EPG + (size_t)b * EPG;
    float* w2 = wrec + 2 * (size_t)NB * EPG + (size_t)b * EPG;
    unsigned char* cdst = clrec + (size_t)b * EPG;
    int c = start;
    for (int e4 = 0; e4 < EPG; e4 += 4) {
        const int4 r4 = *(const int4*)&rl[e4];
        const int rv[4] = {r4.x, r4.y, r4.z, r4.w};
        #pragma unroll
        for (int u = 0; u < 4; ++u) {
            if (rv[u] == t) {
                const int e = e4 + u;
                w0[c] = eap[e * 3 + 0];
                w1[c] = eap[e * 3 + 1];
                w2[c] = eap[e * 3 + 2];
                cdst[c] = clb[e];
                ++c;
            }
        }
    }
}

// ---------------- gconv: 3 layers + combined FC + softmax fused, per (d,b) block ----------------
template<int OUTW, bool WRITE_H>
__device__ __forceinline__ void layer_step(
    int t, int r, int half, int js, int je,
    const float* __restrict__ wp, const unsigned char* __restrict__ clp,
    const float* __restrict__ Wm, const float* __restrict__ Ws,
    const float* __restrict__ bias, const float* __restrict__ wc, // wc + layer_row_off*16
    float4* hb4, float4* ab4, float* t16)
{
    constexpr int NCOL = OUTW / 2;
    __syncthreads();                       // [A] hb stable
    // gather agg[r][half*32 .. +32) from CSR, register-accumulated
    float ga[32];
    #pragma unroll
    for (int u = 0; u < 32; ++u) ga[u] = 0.f;
    const int cb = half * 8;
    for (int j = js; j < je; ++j) {
        const int cl = clp[j];
        const float w = wp[j];
        const int base = cl * 16, sw = cl & 15;
        #pragma unroll
        for (int u = 0; u < 8; ++u) {
            const float4 h4 = hb4[base + ((cb + u) ^ sw)];
            ga[u*4+0] += w * h4.x; ga[u*4+1] += w * h4.y;
            ga[u*4+2] += w * h4.z; ga[u*4+3] += w * h4.w;
        }
    }
    {
        const int base = r * 16, sw = r & 15;
        #pragma unroll
        for (int u = 0; u < 8; ++u) {
            float4 v; v.x = ga[u*4+0]; v.y = ga[u*4+1]; v.z = ga[u*4+2]; v.w = ga[u*4+3];
            ab4[base + ((cb + u) ^ sw)] = v;
        }
    }
    __syncthreads();                       // [B]
    // dense: h_next[r][j0..j0+NCOL) = relu(agg@Wm + h@Ws + b)
    const int j0 = half * NCOL;
    float acc[NCOL];
    #pragma unroll
    for (int jj = 0; jj < NCOL; ++jj) acc[jj] = bias[j0 + jj];
    const int rbase = r * 16, rsw = r & 15;
    for (int ic = 0; ic < 16; ++ic) {
        const float4 a4 = ab4[rbase + (ic ^ rsw)];
        const float4 h4 = hb4[rbase + (ic ^ rsw)];
        const float av[4] = {a4.x, a4.y, a4.z, a4.w};
        const float hv[4] = {h4.x, h4.y, h4.z, h4.w};
        #pragma unroll
        for (int u = 0; u < 4; ++u) {
            const int i = ic * 4 + u;
            const float a = av[u], h = hv[u];
            const float* wmr = Wm + i * OUTW + j0;
            const float* wsr = Ws + i * OUTW + j0;
            #pragma unroll
            for (int q4 = 0; q4 < NCOL / 4; ++q4) {
                const float4 wm4 = *(const float4*)(wmr + q4 * 4);
                const float4 ws4 = *(const float4*)(wsr + q4 * 4);
                acc[q4*4+0] += a * wm4.x + h * ws4.x;
                acc[q4*4+1] += a * wm4.y + h * ws4.y;
                acc[q4*4+2] += a * wm4.z + h * ws4.z;
                acc[q4*4+3] += a * wm4.w + h * ws4.w;
            }
        }
    }
    #pragma unroll
    for (int jj = 0; jj < NCOL; ++jj) acc[jj] = fmaxf(acc[jj], 0.f);
    __syncthreads();                       // [C] all hb/ab reads done
    if (WRITE_H) {
        const int base = r * 16, sw = r & 15;
        #pragma unroll
        for (int u = 0; u < NCOL / 4; ++u) {
            float4 v; v.x = acc[u*4+0]; v.y = acc[u*4+1]; v.z = acc[u*4+2]; v.w = acc[u*4+3];
            hb4[base + ((cb + u) ^ sw)] = v;
        }
    }
    // t16 += h_next @ Wc[layer rows]  (16-wide combined FC)
    #pragma unroll
    for (int jj = 0; jj < NCOL; ++jj) {
        const float hvv = acc[jj];
        const float* wr = wc + (j0 + jj) * 16;
        #pragma unroll
        for (int q4 = 0; q4 < 4; ++q4) {
            const float4 w4 = *(const float4*)(wr + q4 * 4);
            t16[q4*4+0] += hvv * w4.x;
            t16[q4*4+1] += hvv * w4.y;
            t16[q4*4+2] += hvv * w4.z;
            t16[q4*4+3] += hvv * w4.w;
        }
    }
}

__launch_bounds__(512)
__global__ void gconv_kernel(
    const float* __restrict__ x,
    const float* __restrict__ Wm0, const float* __restrict__ Ws0, const float* __restrict__ b0,
    const float* __restrict__ Wm1, const float* __restrict__ Ws1, const float* __restrict__ b1,
    const float* __restrict__ Wm2, const float* __restrict__ Ws2, const float* __restrict__ b2,
    const float* __restrict__ wcomb, const float* __restrict__ bcomb,
    const float* __restrict__ wrec, const unsigned char* __restrict__ clrec,
    const int* __restrict__ indptr,
    float* __restrict__ out, float* __restrict__ entpart)
{
    __shared__ float4 hb4[4096];   // h tile, XOR-chunk-swizzled  (64 KB)
    __shared__ float4 ab4[4096];   // agg tile / t16 exchange     (64 KB)
    __shared__ float  red[8];
    float* ab = (float*)ab4;
    const int t = threadIdx.x;
    const int bid = blockIdx.x;
    const int d = bid >> 8;
    const int b = bid & (NB - 1);
    const int r = t & (NN - 1);
    const int half = t >> 8;
    const int lane = t & 63;
    const int wave = t >> 6;

    // stage x -> hb (swizzled)
    {
        const float4* xv = (const float4*)(x + (size_t)b * NN * HID);
        #pragma unroll
        for (int it = 0; it < 8; ++it) {
            const int idx = t + it * 512;
            const int nrow = idx >> 4, c = idx & 15;
            hb4[nrow * 16 + (c ^ (nrow & 15))] = xv[idx];
        }
    }
    float t16[16];
    #pragma unroll
    for (int q = 0; q < 16; ++q) t16[q] = 0.f;

    const float* wp = wrec + (size_t)d * NB * EPG + (size_t)b * EPG;
    const unsigned char* clp = clrec + (size_t)b * EPG;
    const int js = indptr[b * 257 + r];
    const int je = indptr[b * 257 + r + 1];

    layer_step<64, true >(t, r, half, js, je, wp, clp, Wm0 + d*HID*HID, Ws0 + d*HID*HID,
                          b0 + d*HID, wcomb,            hb4, ab4, t16);
    layer_step<64, true >(t, r, half, js, je, wp, clp, Wm1 + d*HID*HID, Ws1 + d*HID*HID,
                          b1 + d*HID, wcomb + 64*16,    hb4, ab4, t16);
    layer_step<16, false>(t, r, half, js, je, wp, clp, Wm2 + d*HID*KK,  Ws2 + d*HID*KK,
                          b2 + d*KK,  wcomb + 128*16,   hb4, ab4, t16);

    // exchange t16 halves via ab (layout [k][r]: 64 lanes hit 64 distinct banks 2-way)
    __syncthreads();
    if (half == 1) {
        #pragma unroll
        for (int k = 0; k < 16; ++k) ab[(k << 8) + r] = t16[k];
    }
    __syncthreads();
    float ent_local = 0.f;
    if (half == 0) {
        float logits[KK];
        #pragma unroll
        for (int k = 0; k < KK; ++k) logits[k] = t16[k] + ab[(k << 8) + r] + bcomb[k];
        float m = logits[0];
        #pragma unroll
        for (int k = 1; k < KK; ++k) m = fmaxf(m, logits[k]);
        float sum = 0.f, sv[KK];
        #pragma unroll
        for (int k = 0; k < KK; ++k) { sv[k] = expf(logits[k] - m); sum += sv[k]; }
        const float inv = 1.f / sum;
        float* sp = out + S_OFF + ((size_t)(d * NB + b) * NN + r) * KK;
        #pragma unroll
        for (int k = 0; k < KK; ++k) {
            const float s = sv[k] * inv;
            sp[k] = s;
            ent_local -= s * logf(s + 1e-15f);
        }
    }
    #pragma unroll
    for (int off = 32; off; off >>= 1) ent_local += __shfl_down(ent_local, off);
    if (lane == 0) red[wave] = ent_local;
    __syncthreads();
    if (t == 0) {
        float s = 0.f;
        #pragma unroll
        for (int w = 0; w < 8; ++w) s += red[w];
        entpart[bid] = s;
    }
}

// ---------------- pool: padj = sum_r s[r] (x) G[r], G = A s ; + mod + px ----------------
#define SSTR 20
__launch_bounds__(256)
__global__ void pool_kernel(
    const float* __restrict__ x_to_pool,
    const float* __restrict__ wrec, const unsigned char* __restrict__ clrec,
    const int* __restrict__ indptr,
    const float* __restrict__ out_s, float* __restrict__ out, float* __restrict__ modpart)
{
    __shared__ float sl[NN * SSTR];       // 20 KB
    __shared__ float gl[NN * SSTR];       // 20 KB
    __shared__ float padjw[4 * 256];      // per-wave partials (deterministic merge)
    __shared__ float red[4];
    const int t = threadIdx.x;
    const int bid = blockIdx.x;
    const int d = bid >> 8;
    const int b = bid & (NB - 1);
    const int lane = t & 63;
    const int wave = t >> 6;

    {
        const float4* sp4 = (const float4*)(out_s + S_OFF + (size_t)(d * NB + b) * NN * KK);
        #pragma unroll
        for (int it = 0; it < 4; ++it) {
            const int idx = t + it * 256;
            const int nrow = idx >> 2, c = idx & 3;
            *(float4*)(sl + nrow * SSTR + c * 4) = sp4[idx];
        }
    }
    __syncthreads();

    const float* wp = wrec + (size_t)d * NB * EPG + (size_t)b * EPG;
    const unsigned char* clp = clrec + (size_t)b * EPG;
    const int js = indptr[b * 257 + t];
    const int je = indptr[b * 257 + t + 1];
    float sr[16];
    {
        #pragma unroll
        for (int c = 0; c < 4; ++c) {
            const float4 v = *(const float4*)(sl + t * SSTR + c * 4);
            sr[c*4+0] = v.x; sr[c*4+1] = v.y; sr[c*4+2] = v.z; sr[c*4+3] = v.w;
        }
    }
    float g[16];
    #pragma unroll
    for (int k = 0; k < 16; ++k) g[k] = 0.f;
    float modacc = 0.f;
    for (int j = js; j < je; ++j) {
        const int cl = clp[j];
        const float w = wp[j];
        const float* srow = sl + cl * SSTR;
        float ss = 0.f;
        #pragma unroll
        for (int c = 0; c < 4; ++c) {
            const float4 sv = *(const float4*)(srow + c * 4);
            g[c*4+0] += w * sv.x; g[c*4+1] += w * sv.y;
            g[c*4+2] += w * sv.z; g[c*4+3] += w * sv.w;
            const float d0 = sr[c*4+0] - sv.x, d1 = sr[c*4+1] - sv.y;
            const float d2 = sr[c*4+2] - sv.z, d3 = sr[c*4+3] - sv.w;
            ss += d0*d0 + d1*d1 + d2*d2 + d3*d3;
        }
        modacc += w * ss;
    }
    {
        #pragma unroll
        for (int c = 0; c < 4; ++c) {
            float4 v; v.x = g[c*4+0]; v.y = g[c*4+1]; v.z = g[c*4+2]; v.w = g[c*4+3];
            *(float4*)(gl + t * SSTR + c * 4) = v;
        }
    }
    __syncthreads();

    // padj[k][l] = sum_r s[r][k] * G[r][l]; wave w covers r in [w*64, w*64+64)
    {
        const int k = t & 15, lg = (t >> 4) & 3;
        float p0 = 0.f, p1 = 0.f, p2 = 0.f, p3 = 0.f;
        const int r0 = wave * 64;
        for (int rr = r0; rr < r0 + 64; ++rr) {
            const float sk = sl[rr * SSTR + k];
            const float4 g4 = *(const float4*)(gl + rr * SSTR + lg * 4);
            p0 += sk * g4.x; p1 += sk * g4.y; p2 += sk * g4.z; p3 += sk * g4.w;
        }
        float* pw = padjw + wave * 256 + k * 16 + lg * 4;
        pw[0] = p0; pw[1] = p1; pw[2] = p2; pw[3] = p3;
    }

    // px[k][f] = sum_n s[n][k] * xtp[n][f*3+d]
    {
        const int f = t & 63;
        const int kg = t >> 6;
        float xa0 = 0.f, xa1 = 0.f, xa2 = 0.f, xa3 = 0.f;
        const float* xp = x_to_pool + (size_t)b * NN * (64 * DIMS) + f * DIMS + d;
        #pragma unroll 4
        for (int nn2 = 0; nn2 < NN; ++nn2) {
            const float xv = xp[(size_t)nn2 * (64 * DIMS)];
            const float4 s4 = *(const float4*)(sl + nn2 * SSTR + kg * 4);
            xa0 += xv * s4.x; xa1 += xv * s4.y; xa2 += xv * s4.z; xa3 += xv * s4.w;
        }
        const float sc = 1.f / 16.f;  // K/N
        out[PX_OFF + ((size_t)((b * KK + kg * 4 + 0) * 64) + f) * DIMS + d] = xa0 * sc;
        out[PX_OFF + ((size_t)((b * KK + kg * 4 + 1) * 64) + f) * DIMS + d] = xa1 * sc;
        out[PX_OFF + ((size_t)((b * KK + kg * 4 + 2) * 64) + f) * DIMS + d] = xa2 * sc;
        out[PX_OFF + ((size_t)((b * KK + kg * 4 + 3) * 64) + f) * DIMS + d] = xa3 * sc;
    }

    #pragma unroll
    for (int off = 32; off; off >>= 1) modacc += __shfl_down(modacc, off);
    if (lane == 0) red[wave] = modacc;
    __syncthreads();   // also fences padjw
    if (t == 0) modpart[bid] = red[0] + red[1] + red[2] + red[3];

    {
        const float v = (padjw[t] + padjw[256 + t] + padjw[512 + t] + padjw[768 + t]) * (1.f / 256.f);
        out[PEA_OFF + (size_t)((b * KK + (t >> 4)) * KK + (t & 15)) * DIMS + d] = v;
    }
}

__global__ void aux_kernel(float* __restrict__ out)
{
    const int idx = blockIdx.x * 256 + threadIdx.x;
    if (idx < 2 * NTOT) {
        const int r = idx & (NTOT - 1);
        const int bb = r >> 8;
        const int j = r & 255;
        const int v = (idx < NTOT) ? (bb * KK + (j >> 4)) : (bb * KK + (j & 15));
        out[PEI_OFF + idx] = (float)v;
    } else if (idx < 2 * NTOT + NB * KK) {
        const int i = idx - 2 * NTOT;
        out[PB_OFF + i] = (float)(i >> 4);
    }
}

__global__ void loss_kernel(const float* __restrict__ entpart,
                            const float* __restrict__ modpart,
                            float* __restrict__ out)
{
    const int tid = threadIdx.x;
    float e = 0.f, m = 0.f;
    for (int i = tid; i < DIMS * NB; i += 256) { e += entpart[i]; m += modpart[i]; }
    #pragma unroll
    for (int off = 32; off; off >>= 1) { e += __shfl_down(e, off); m += __shfl_down(m, off); }
    __shared__ float er[4], mr[4];
    const int wave = tid >> 6, lane = tid & 63;
    if (lane == 0) { er[wave] = e; mr[wave] = m; }
    __syncthreads();
    if (tid == 0) {
        const float es = er[0] + er[1] + er[2] + er[3];
        const float ms = mr[0] + mr[1] + mr[2] + mr[3];
        out[LOSS_OFF] = ms / (float)NE + es / (float)(DIMS * NTOT);
    }
}

extern "C" void kernel_launch(void* const* d_in, const int* in_sizes, int n_in,
                              void* d_out, int out_size, void* d_ws, size_t ws_size,
                              hipStream_t stream)
{
    const float* x         = (const float*)d_in[0];
    const float* edge_attr = (const float*)d_in[1];
    const float* x_to_pool = (const float*)d_in[2];
    const float* Wm0 = (const float*)d_in[3];
    const float* Ws0 = (const float*)d_in[4];
    const float* b0  = (const float*)d_in[5];
    const float* Wm1 = (const float*)d_in[6];
    const float* Ws1 = (const float*)d_in[7];
    const float* b1  = (const float*)d_in[8];
    const float* Wm2 = (const float*)d_in[9];
    const float* Ws2 = (const float*)d_in[10];
    const float* b2  = (const float*)d_in[11];
    const float* fcW1= (const float*)d_in[12];
    const float* fcb1= (const float*)d_in[13];
    const float* fcW2= (const float*)d_in[14];
    const float* fcb2= (const float*)d_in[15];
    const int* edge_index = (const int*)d_in[16];
    float* out = (float*)d_out;
    char* ws = (char*)d_ws;
    float*         wrec  = (float*)(ws + WREC_WS);
    unsigned char* clrec = (unsigned char*)(ws + CLREC_WS);
    int*           iptr  = (int*)(ws + IPTR_WS);
    float*         entpart = (float*)(ws + ENT_WS);
    float*         modpart = (float*)(ws + MOD_WS);
    float*         wc    = (float*)(ws + WC_WS);
    float*         bc    = (float*)(ws + BC_WS);

    csr_build<<<dim3(NB), dim3(256), 0, stream>>>(edge_index, edge_attr, wrec, clrec, iptr);
    fc_combine<<<dim3(1), dim3(256), 0, stream>>>(fcW1, fcb1, fcW2, fcb2, wc, bc);
    gconv_kernel<<<dim3(DIMS * NB), dim3(512), 0, stream>>>(
        x, Wm0, Ws0, b0, Wm1, Ws1, b1, Wm2, Ws2, b2,
        wc, bc, wrec, clrec, iptr, out, entpart);
    pool_kernel<<<dim3(DIMS * NB), dim3(256), 0, stream>>>(
        x_to_pool, wrec, clrec, iptr, out, out, modpart);
    aux_kernel<<<dim3((2 * NTOT + NB * KK + 255) / 256), dim3(256), 0, stream>>>(out);
    loss_kernel<<<dim3(1), dim3(256), 0, stream>>>(entpart, modpart, out);
}